// Round 1
// baseline (1796.868 us; speedup 1.0000x reference)
//
#include <hip/hip_runtime.h>
#include <math.h>

#define EPSF 1e-6f
#define NV 8

__device__ __constant__ int DISK[37] = {
    2, 3, 4,
    8, 9, 10, 11, 12,
    14, 15, 16, 17, 18, 19, 20,
    21, 22, 23, 24, 25, 26, 27,
    28, 29, 30, 31, 32, 33, 34,
    36, 37, 38, 39, 40,
    44, 45, 46};

// ---------------------------------------------------------------------------
// Phase A precompute: g[n, d, rm] = sum_c Wc[d, c, rm] * x[n, c]
// Wc[d,c,rm] = W_conv[d,c,rm] * exp(i*phase[d,c])
// g stored interleaved float2, layout [n][d*18+rm]
// ---------------------------------------------------------------------------
__global__ __launch_bounds__(256) void g_kernel(
    const float* __restrict__ x_re, const float* __restrict__ x_im,
    const float* __restrict__ W_conv, const float* __restrict__ phase,
    float2* __restrict__ g2, int N) {
  __shared__ float wc_re[1152];
  __shared__ float wc_im[1152];
  int t = threadIdx.x;
  for (int i = t; i < 1152; i += 256) {
    int dc = i / 18;  // d*8 + c  (W_conv layout (D,C,R,M) flat = d*144 + c*18 + rm)
    float w = W_conv[i];
    float ph = phase[dc];
    wc_re[i] = w * cosf(ph);
    wc_im[i] = w * sinf(ph);
  }
  __syncthreads();
  int gid = blockIdx.x * 256 + t;
  int total = N * 144;
  if (gid >= total) return;
  int n = gid / 144;
  int q = gid - n * 144;  // d*18 + rm
  int d = q / 18;
  int rm = q - d * 18;
  const float* xr = x_re + n * 8;
  const float* xi = x_im + n * 8;
  float ar = 0.f, ai = 0.f;
#pragma unroll
  for (int c = 0; c < 8; ++c) {
    float wr = wc_re[(d * 8 + c) * 18 + rm];
    float wi = wc_im[(d * 8 + c) * 18 + rm];
    float vr = xr[c], vi = xi[c];
    ar += wr * vr - wi * vi;
    ai += wr * vi + wi * vr;
  }
  g2[gid] = make_float2(ar, ai);
}

// ---------------------------------------------------------------------------
// Phase A edge conv: ye[e,d] = sum_rm S[e,rm] * g[src,d,rm]; scatter-add to y[dst]
// y stored interleaved: y[n*16 + 2*d] = re, +1 = im
// ---------------------------------------------------------------------------
__global__ __launch_bounds__(256) void edge_conv_kernel(
    const int* __restrict__ edges,
    const float* __restrict__ sten_re, const float* __restrict__ sten_im,
    const float2* __restrict__ g2, float* __restrict__ y, int E) {
  int e = blockIdx.x * 256 + threadIdx.x;
  if (e >= E) return;
  int src = edges[2 * e];
  int dst = edges[2 * e + 1];
  float sr[18], si[18];
  const float2* pre = (const float2*)(sten_re + (size_t)e * 18);
  const float2* pim = (const float2*)(sten_im + (size_t)e * 18);
#pragma unroll
  for (int i = 0; i < 9; ++i) {
    float2 a = pre[i];
    float2 b = pim[i];
    sr[2 * i] = a.x; sr[2 * i + 1] = a.y;
    si[2 * i] = b.x; si[2 * i + 1] = b.y;
  }
  const float2* gp = g2 + (size_t)src * 144;
  for (int d = 0; d < 8; ++d) {
    float ar = 0.f, ai = 0.f;
    const float4* gq = (const float4*)(gp + d * 18);
#pragma unroll
    for (int p = 0; p < 9; ++p) {
      float4 gv = gq[p];  // two complex values
      int rm = 2 * p;
      ar += sr[rm] * gv.x - si[rm] * gv.y;
      ai += sr[rm] * gv.y + si[rm] * gv.x;
      ar += sr[rm + 1] * gv.z - si[rm + 1] * gv.w;
      ai += sr[rm + 1] * gv.w + si[rm + 1] * gv.z;
    }
    atomicAdd(&y[(size_t)dst * 16 + 2 * d], ar);
    atomicAdd(&y[(size_t)dst * 16 + 2 * d + 1], ai);
  }
}

// ---------------------------------------------------------------------------
// Phase B: per-(n,d) magnitude nonlinearity, in place on y
// ---------------------------------------------------------------------------
__global__ __launch_bounds__(256) void nl_kernel(float* __restrict__ y,
                                                 const float* __restrict__ b_nl,
                                                 int ND) {
  int i = blockIdx.x * 256 + threadIdx.x;
  if (i >= ND) return;
  int d = i & 7;
  float yr = y[2 * i], yi = y[2 * i + 1];
  float mag = sqrtf(yr * yr + yi * yi);
  float s = fmaxf(mag + b_nl[d], 0.f) / (mag + EPSF);
  y[2 * i] = yr * s;
  y[2 * i + 1] = yi * s;
}

// ---------------------------------------------------------------------------
// Phase C: per-edge bilinear histogram scatter
// hist layout: [n][gi=xi*7+yi][d]  (N x 49 x 8 floats)
// ---------------------------------------------------------------------------
__global__ __launch_bounds__(256) void hist_kernel(
    const int* __restrict__ edges, const float* __restrict__ y,
    const float* __restrict__ ln_re, const float* __restrict__ ln_im,
    const float* __restrict__ wxp_re, const float* __restrict__ wxp_im,
    float* __restrict__ hist, int E) {
  int e = blockIdx.x * 256 + threadIdx.x;
  if (e >= E) return;
  int src = edges[2 * e];
  int dst = edges[2 * e + 1];
  float wr = wxp_re[e], wi = wxp_im[e];
  float lr = ln_re[e], li = ln_im[e];
  float* hrow = hist + (size_t)dst * 392;
  const float4* yp = (const float4*)(y + (size_t)src * 16);
#pragma unroll
  for (int p = 0; p < 4; ++p) {
    float4 yv = yp[p];  // two complex channel values
#pragma unroll
    for (int h = 0; h < 2; ++h) {
      int d = 2 * p + h;
      float yr = h ? yv.z : yv.x;
      float yi = h ? yv.w : yv.y;
      float fr = yr * wr - yi * wi;
      float fi = yr * wi + yi * wr;
      float fm = sqrtf(fr * fr + fi * fi);
      float inv = 1.f / (fm + EPSF);
      float cr = (lr * fr + li * fi) * inv;  // (ln * conj(f)).re
      float ci = (li * fr - lr * fi) * inv;  // (ln * conj(f)).im
      float gx = cr * 3.f + 3.f;
      float gy = ci * 3.f + 3.f;
      float x0f = floorf(gx), y0f = floorf(gy);
      float wx = gx - x0f, wy = gy - y0f;
      int x0i = min(max((int)x0f, 0), 6);
      int x1i = min(x0i + 1, 6);
      int y0i = min(max((int)y0f, 0), 6);
      int y1i = min(y0i + 1, 6);
      float w00 = fm * (1.f - wx) * (1.f - wy);
      float w10 = fm * wx * (1.f - wy);
      float w01 = fm * (1.f - wx) * wy;
      float w11 = fm * wx * wy;
      atomicAdd(hrow + (x0i * 7 + y0i) * 8 + d, w00);
      atomicAdd(hrow + (x1i * 7 + y0i) * 8 + d, w10);
      atomicAdd(hrow + (x0i * 7 + y1i) * 8 + d, w01);
      atomicAdd(hrow + (x1i * 7 + y1i) * 8 + d, w11);
    }
  }
}

// ---------------------------------------------------------------------------
// Phase D: disk gather + MLP (296 -> 128 -> 64 -> 64) + residual
// 128 threads per block, NV=8 nodes per block
// ---------------------------------------------------------------------------
__global__ __launch_bounds__(128) void mlp_kernel(
    const float* __restrict__ hist,
    const float* __restrict__ x_re, const float* __restrict__ x_im,
    const float* __restrict__ W1, const float* __restrict__ b1,
    const float* __restrict__ W2, const float* __restrict__ b2,
    const float* __restrict__ W3, const float* __restrict__ b3,
    const float* __restrict__ Wres, const float* __restrict__ bres,
    float* __restrict__ out, int N) {
  __shared__ float desc[NV][296];
  __shared__ float h1s[NV][128];
  __shared__ float h2s[NV][64];
  __shared__ float rmag[NV][8];
  int t = threadIdx.x;
  int n0 = blockIdx.x * NV;

  for (int i = t; i < NV * 296; i += 128) {
    int v = i / 296;
    int q = i - v * 296;
    int d = q / 37;
    int k = q - d * 37;
    int n = n0 + v;
    desc[v][q] = (n < N) ? hist[(size_t)n * 392 + DISK[k] * 8 + d] : 0.f;
  }
  if (t < NV * 8) {
    int v = t >> 3, c = t & 7;
    int n = n0 + v;
    if (n < N) {
      float xr = x_re[n * 8 + c], xi = x_im[n * 8 + c];
      rmag[v][c] = sqrtf(xr * xr + xi * xi + EPSF);
    } else {
      rmag[v][c] = 0.f;
    }
  }
  __syncthreads();

  // Layer 1: h1[v][t] = relu(b1[t] + dot(desc[v], W1[t]))
  {
    float acc[NV];
    float bb = b1[t];
#pragma unroll
    for (int v = 0; v < NV; ++v) acc[v] = bb;
    const float* wrow = W1 + (size_t)t * 296;
    for (int k = 0; k < 296; k += 8) {
      float4 wa = *(const float4*)(wrow + k);
      float4 wb = *(const float4*)(wrow + k + 4);
#pragma unroll
      for (int v = 0; v < NV; ++v) {
        acc[v] += wa.x * desc[v][k] + wa.y * desc[v][k + 1] +
                  wa.z * desc[v][k + 2] + wa.w * desc[v][k + 3] +
                  wb.x * desc[v][k + 4] + wb.y * desc[v][k + 5] +
                  wb.z * desc[v][k + 6] + wb.w * desc[v][k + 7];
      }
    }
#pragma unroll
    for (int v = 0; v < NV; ++v) h1s[v][t] = fmaxf(acc[v], 0.f);
  }
  __syncthreads();

  // Layer 2: h2[v][t] = relu(b2[t] + dot(h1[v], W2[t])), t < 64
  if (t < 64) {
    float acc[NV];
    float bb = b2[t];
#pragma unroll
    for (int v = 0; v < NV; ++v) acc[v] = bb;
    const float* wrow = W2 + (size_t)t * 128;
    for (int k = 0; k < 128; k += 8) {
      float4 wa = *(const float4*)(wrow + k);
      float4 wb = *(const float4*)(wrow + k + 4);
#pragma unroll
      for (int v = 0; v < NV; ++v) {
        acc[v] += wa.x * h1s[v][k] + wa.y * h1s[v][k + 1] +
                  wa.z * h1s[v][k + 2] + wa.w * h1s[v][k + 3] +
                  wb.x * h1s[v][k + 4] + wb.y * h1s[v][k + 5] +
                  wb.z * h1s[v][k + 6] + wb.w * h1s[v][k + 7];
      }
    }
#pragma unroll
    for (int v = 0; v < NV; ++v) h2s[v][t] = fmaxf(acc[v], 0.f);
  }
  __syncthreads();

  // Layer 3 + residual: out[n][t] = b3[t] + dot(h2[v], W3[t]) + bres[t] + dot(rmag[v], Wres[t])
  if (t < 64) {
    float acc[NV];
    float bb = b3[t] + bres[t];
#pragma unroll
    for (int v = 0; v < NV; ++v) acc[v] = bb;
    const float* wrow = W3 + (size_t)t * 64;
    for (int k = 0; k < 64; k += 8) {
      float4 wa = *(const float4*)(wrow + k);
      float4 wb = *(const float4*)(wrow + k + 4);
#pragma unroll
      for (int v = 0; v < NV; ++v) {
        acc[v] += wa.x * h2s[v][k] + wa.y * h2s[v][k + 1] +
                  wa.z * h2s[v][k + 2] + wa.w * h2s[v][k + 3] +
                  wb.x * h2s[v][k + 4] + wb.y * h2s[v][k + 5] +
                  wb.z * h2s[v][k + 6] + wb.w * h2s[v][k + 7];
      }
    }
    float wrr[8];
    const float* wp = Wres + (size_t)t * 8;
#pragma unroll
    for (int c = 0; c < 8; ++c) wrr[c] = wp[c];
#pragma unroll
    for (int v = 0; v < NV; ++v) {
#pragma unroll
      for (int c = 0; c < 8; ++c) acc[v] += wrr[c] * rmag[v][c];
    }
#pragma unroll
    for (int v = 0; v < NV; ++v) {
      int n = n0 + v;
      if (n < N) out[(size_t)n * 64 + t] = acc[v];
    }
  }
}

extern "C" void kernel_launch(void* const* d_in, const int* in_sizes, int n_in,
                              void* d_out, int out_size, void* d_ws, size_t ws_size,
                              hipStream_t stream) {
  (void)n_in; (void)out_size; (void)ws_size;
  const float* x_re = (const float*)d_in[0];
  const float* x_im = (const float*)d_in[1];
  const int* edges = (const int*)d_in[2];
  const float* sten_re = (const float*)d_in[3];
  const float* sten_im = (const float*)d_in[4];
  const float* ln_re = (const float*)d_in[5];
  const float* ln_im = (const float*)d_in[6];
  const float* wxp_re = (const float*)d_in[7];
  const float* wxp_im = (const float*)d_in[8];
  const float* W_conv = (const float*)d_in[9];
  const float* phase = (const float*)d_in[10];
  const float* b_nl = (const float*)d_in[11];
  const float* W1 = (const float*)d_in[12];
  const float* b1 = (const float*)d_in[13];
  const float* W2 = (const float*)d_in[14];
  const float* b2 = (const float*)d_in[15];
  const float* W3 = (const float*)d_in[16];
  const float* b3 = (const float*)d_in[17];
  const float* Wres = (const float*)d_in[18];
  const float* bres = (const float*)d_in[19];
  float* out = (float*)d_out;

  int N = in_sizes[0] / 8;
  int E = in_sizes[2] / 2;

  float* ws = (float*)d_ws;
  float2* g2 = (float2*)ws;                    // N*144 float2 = N*288 floats
  float* y = ws + (size_t)N * 288;             // N*16 floats (interleaved complex)
  float* hist = y + (size_t)N * 16;            // N*392 floats

  hipMemsetAsync(y, 0, (size_t)N * 16 * sizeof(float), stream);
  hipMemsetAsync(hist, 0, (size_t)N * 392 * sizeof(float), stream);

  g_kernel<<<(N * 144 + 255) / 256, 256, 0, stream>>>(x_re, x_im, W_conv, phase, g2, N);
  edge_conv_kernel<<<(E + 255) / 256, 256, 0, stream>>>(edges, sten_re, sten_im, g2, y, E);
  nl_kernel<<<(N * 8 + 255) / 256, 256, 0, stream>>>(y, b_nl, N * 8);
  hist_kernel<<<(E + 255) / 256, 256, 0, stream>>>(edges, y, ln_re, ln_im, wxp_re, wxp_im, hist, E);
  mlp_kernel<<<(N + NV - 1) / NV, 128, 0, stream>>>(hist, x_re, x_im, W1, b1, W2, b2,
                                                    W3, b3, Wres, bres, out, N);
}

// Round 2
// 975.113 us; speedup vs baseline: 1.8427x; 1.8427x over previous
//
#include <hip/hip_runtime.h>
#include <math.h>

#define EPSF 1e-6f
#define NV 8

__device__ __constant__ int DISK[37] = {
    2, 3, 4,
    8, 9, 10, 11, 12,
    14, 15, 16, 17, 18, 19, 20,
    21, 22, 23, 24, 25, 26, 27,
    28, 29, 30, 31, 32, 33, 34,
    36, 37, 38, 39, 40,
    44, 45, 46};

// ---------------------------------------------------------------------------
// g[n, d, rm] = sum_c Wc[d, c, rm] * x[n, c];  Wc = W_conv * exp(i*phase)
// g stored interleaved float2, layout [n][d*18+rm]
// ---------------------------------------------------------------------------
__global__ __launch_bounds__(256) void g_kernel(
    const float* __restrict__ x_re, const float* __restrict__ x_im,
    const float* __restrict__ W_conv, const float* __restrict__ phase,
    float2* __restrict__ g2, int N) {
  __shared__ float wc_re[1152];
  __shared__ float wc_im[1152];
  int t = threadIdx.x;
  for (int i = t; i < 1152; i += 256) {
    int dc = i / 18;
    float w = W_conv[i];
    float ph = phase[dc];
    wc_re[i] = w * cosf(ph);
    wc_im[i] = w * sinf(ph);
  }
  __syncthreads();
  int gid = blockIdx.x * 256 + t;
  int total = N * 144;
  if (gid >= total) return;
  int n = gid / 144;
  int q = gid - n * 144;  // d*18 + rm
  int d = q / 18;
  int rm = q - d * 18;
  const float* xr = x_re + n * 8;
  const float* xi = x_im + n * 8;
  float ar = 0.f, ai = 0.f;
#pragma unroll
  for (int c = 0; c < 8; ++c) {
    float wr = wc_re[(d * 8 + c) * 18 + rm];
    float wi = wc_im[(d * 8 + c) * 18 + rm];
    float vr = xr[c], vi = xi[c];
    ar += wr * vr - wi * vi;
    ai += wr * vi + wi * vr;
  }
  g2[gid] = make_float2(ar, ai);
}

// ---------------------------------------------------------------------------
// CSR build: count incoming edges per dst
// ---------------------------------------------------------------------------
__global__ __launch_bounds__(256) void count_kernel(const int* __restrict__ edges,
                                                    int* __restrict__ cnt, int E) {
  int e = blockIdx.x * 256 + threadIdx.x;
  if (e >= E) return;
  atomicAdd(&cnt[edges[2 * e + 1]], 1);
}

// Single-block exclusive scan of cnt[N] -> offs[N+1], also init cur = offs
__global__ __launch_bounds__(1024) void scan_kernel(const int* __restrict__ cnt,
                                                    int* __restrict__ offs,
                                                    int* __restrict__ cur, int N) {
  __shared__ int sums[1024];
  int t = threadIdx.x;
  int per = (N + 1023) / 1024;
  int base = t * per;
  int s = 0;
  for (int i = 0; i < per; ++i) {
    int idx = base + i;
    if (idx < N) s += cnt[idx];
  }
  sums[t] = s;
  __syncthreads();
  for (int d = 1; d < 1024; d <<= 1) {
    int v = (t >= d) ? sums[t - d] : 0;
    __syncthreads();
    sums[t] += v;
    __syncthreads();
  }
  int run = (t == 0) ? 0 : sums[t - 1];
  for (int i = 0; i < per; ++i) {
    int idx = base + i;
    if (idx < N) {
      offs[idx] = run;
      cur[idx] = run;
      run += cnt[idx];
    }
  }
  if (t == 1023) offs[N] = sums[1023];
}

__global__ __launch_bounds__(256) void fill_kernel(const int* __restrict__ edges,
                                                   int* __restrict__ cur,
                                                   int* __restrict__ elist, int E) {
  int e = blockIdx.x * 256 + threadIdx.x;
  if (e >= E) return;
  int pos = atomicAdd(&cur[edges[2 * e + 1]], 1);
  elist[pos] = e;
}

// ---------------------------------------------------------------------------
// Gather edge conv + nonlinearity: one wave per node.
// lane = es*8 + d; es strides over incoming edges; butterfly-reduce over es.
// y[n*16+2d] = re, +1 = im (post-nonlinearity)
// ---------------------------------------------------------------------------
__global__ __launch_bounds__(64) void edge_conv_gather(
    const int* __restrict__ edges, const int* __restrict__ offs,
    const int* __restrict__ elist,
    const float* __restrict__ sten_re, const float* __restrict__ sten_im,
    const float2* __restrict__ g2, const float* __restrict__ b_nl,
    float* __restrict__ y, int N) {
  int n = blockIdx.x;
  int lane = threadIdx.x;
  int es = lane >> 3;
  int d = lane & 7;
  int beg = offs[n], end = offs[n + 1];
  float ar = 0.f, ai = 0.f;
  for (int i = beg + es; i < end; i += 8) {
    int e = elist[i];
    int src = edges[2 * e];
    float sr[18], si[18];
    const float2* pre = (const float2*)(sten_re + (size_t)e * 18);
    const float2* pim = (const float2*)(sten_im + (size_t)e * 18);
#pragma unroll
    for (int p = 0; p < 9; ++p) {
      float2 a = pre[p];
      float2 b = pim[p];
      sr[2 * p] = a.x; sr[2 * p + 1] = a.y;
      si[2 * p] = b.x; si[2 * p + 1] = b.y;
    }
    const float4* gq = (const float4*)(g2 + (size_t)src * 144 + d * 18);
#pragma unroll
    for (int p = 0; p < 9; ++p) {
      float4 gv = gq[p];
      int rm = 2 * p;
      ar += sr[rm] * gv.x - si[rm] * gv.y;
      ai += sr[rm] * gv.y + si[rm] * gv.x;
      ar += sr[rm + 1] * gv.z - si[rm + 1] * gv.w;
      ai += sr[rm + 1] * gv.w + si[rm + 1] * gv.z;
    }
  }
  // reduce over es (lanes d, d+8, ..., d+56)
  ar += __shfl_xor(ar, 8);
  ai += __shfl_xor(ai, 8);
  ar += __shfl_xor(ar, 16);
  ai += __shfl_xor(ai, 16);
  ar += __shfl_xor(ar, 32);
  ai += __shfl_xor(ai, 32);
  if (lane < 8) {
    float mag = sqrtf(ar * ar + ai * ai);
    float s = fmaxf(mag + b_nl[d], 0.f) / (mag + EPSF);
    y[(size_t)n * 16 + 2 * d] = ar * s;
    y[(size_t)n * 16 + 2 * d + 1] = ai * s;
  }
}

// ---------------------------------------------------------------------------
// Fused histogram (LDS atomics, per-node gather) + disk-gather + MLP + residual
// 256 threads, NV=8 nodes per block; 32 threads serve each node's edges.
// ---------------------------------------------------------------------------
__global__ __launch_bounds__(256) void hist_mlp_kernel(
    const int* __restrict__ edges, const int* __restrict__ offs,
    const int* __restrict__ elist, const float* __restrict__ y,
    const float* __restrict__ ln_re, const float* __restrict__ ln_im,
    const float* __restrict__ wxp_re, const float* __restrict__ wxp_im,
    const float* __restrict__ x_re, const float* __restrict__ x_im,
    const float* __restrict__ W1, const float* __restrict__ b1,
    const float* __restrict__ W2, const float* __restrict__ b2,
    const float* __restrict__ W3, const float* __restrict__ b3,
    const float* __restrict__ Wres, const float* __restrict__ bres,
    float* __restrict__ out, int N) {
  __shared__ float hl[NV][392];
  __shared__ float desc[NV][296];
  __shared__ float h1s[NV][128];
  __shared__ float h2s[NV][64];
  __shared__ float rmag[NV][8];
  int t = threadIdx.x;
  int n0 = blockIdx.x * NV;

  for (int i = t; i < NV * 392; i += 256) ((float*)hl)[i] = 0.f;
  if (t < NV * 8) {
    int v = t >> 3, c = t & 7;
    int n = n0 + v;
    if (n < N) {
      float xr = x_re[n * 8 + c], xi = x_im[n * 8 + c];
      rmag[v][c] = sqrtf(xr * xr + xi * xi + EPSF);
    } else {
      rmag[v][c] = 0.f;
    }
  }
  __syncthreads();

  // histogram phase: 32 lanes per node
  {
    int v = t >> 5;
    int l = t & 31;
    int n = n0 + v;
    if (n < N) {
      int beg = offs[n], end = offs[n + 1];
      for (int i = beg + l; i < end; i += 32) {
        int e = elist[i];
        int src = edges[2 * e];
        float wr = wxp_re[e], wi = wxp_im[e];
        float lr = ln_re[e], li = ln_im[e];
        const float4* yp = (const float4*)(y + (size_t)src * 16);
#pragma unroll
        for (int p = 0; p < 4; ++p) {
          float4 yv = yp[p];
#pragma unroll
          for (int h = 0; h < 2; ++h) {
            int d = 2 * p + h;
            float yr = h ? yv.z : yv.x;
            float yi = h ? yv.w : yv.y;
            float fr = yr * wr - yi * wi;
            float fi = yr * wi + yi * wr;
            float fm = sqrtf(fr * fr + fi * fi);
            float inv = 1.f / (fm + EPSF);
            float cr = (lr * fr + li * fi) * inv;
            float ci = (li * fr - lr * fi) * inv;
            float gx = cr * 3.f + 3.f;
            float gy = ci * 3.f + 3.f;
            float x0f = floorf(gx), y0f = floorf(gy);
            float wx = gx - x0f, wy = gy - y0f;
            int x0i = min(max((int)x0f, 0), 6);
            int x1i = min(x0i + 1, 6);
            int y0i = min(max((int)y0f, 0), 6);
            int y1i = min(y0i + 1, 6);
            atomicAdd(&hl[v][(x0i * 7 + y0i) * 8 + d], fm * (1.f - wx) * (1.f - wy));
            atomicAdd(&hl[v][(x1i * 7 + y0i) * 8 + d], fm * wx * (1.f - wy));
            atomicAdd(&hl[v][(x0i * 7 + y1i) * 8 + d], fm * (1.f - wx) * wy);
            atomicAdd(&hl[v][(x1i * 7 + y1i) * 8 + d], fm * wx * wy);
          }
        }
      }
    }
  }
  __syncthreads();

  // disk gather into desc
  for (int i = t; i < NV * 296; i += 256) {
    int v = i / 296;
    int q = i - v * 296;
    int d = q / 37;
    int k = q - d * 37;
    desc[v][q] = hl[v][DISK[k] * 8 + d];
  }
  __syncthreads();

  // Layer 1
  if (t < 128) {
    float acc[NV];
    float bb = b1[t];
#pragma unroll
    for (int v = 0; v < NV; ++v) acc[v] = bb;
    const float* wrow = W1 + (size_t)t * 296;
    for (int k = 0; k < 296; k += 8) {
      float4 wa = *(const float4*)(wrow + k);
      float4 wb = *(const float4*)(wrow + k + 4);
#pragma unroll
      for (int v = 0; v < NV; ++v) {
        acc[v] += wa.x * desc[v][k] + wa.y * desc[v][k + 1] +
                  wa.z * desc[v][k + 2] + wa.w * desc[v][k + 3] +
                  wb.x * desc[v][k + 4] + wb.y * desc[v][k + 5] +
                  wb.z * desc[v][k + 6] + wb.w * desc[v][k + 7];
      }
    }
#pragma unroll
    for (int v = 0; v < NV; ++v) h1s[v][t] = fmaxf(acc[v], 0.f);
  }
  __syncthreads();

  // Layer 2
  if (t < 64) {
    float acc[NV];
    float bb = b2[t];
#pragma unroll
    for (int v = 0; v < NV; ++v) acc[v] = bb;
    const float* wrow = W2 + (size_t)t * 128;
    for (int k = 0; k < 128; k += 8) {
      float4 wa = *(const float4*)(wrow + k);
      float4 wb = *(const float4*)(wrow + k + 4);
#pragma unroll
      for (int v = 0; v < NV; ++v) {
        acc[v] += wa.x * h1s[v][k] + wa.y * h1s[v][k + 1] +
                  wa.z * h1s[v][k + 2] + wa.w * h1s[v][k + 3] +
                  wb.x * h1s[v][k + 4] + wb.y * h1s[v][k + 5] +
                  wb.z * h1s[v][k + 6] + wb.w * h1s[v][k + 7];
      }
    }
#pragma unroll
    for (int v = 0; v < NV; ++v) h2s[v][t] = fmaxf(acc[v], 0.f);
  }
  __syncthreads();

  // Layer 3 + residual
  if (t < 64) {
    float acc[NV];
    float bb = b3[t] + bres[t];
#pragma unroll
    for (int v = 0; v < NV; ++v) acc[v] = bb;
    const float* wrow = W3 + (size_t)t * 64;
    for (int k = 0; k < 64; k += 8) {
      float4 wa = *(const float4*)(wrow + k);
      float4 wb = *(const float4*)(wrow + k + 4);
#pragma unroll
      for (int v = 0; v < NV; ++v) {
        acc[v] += wa.x * h2s[v][k] + wa.y * h2s[v][k + 1] +
                  wa.z * h2s[v][k + 2] + wa.w * h2s[v][k + 3] +
                  wb.x * h2s[v][k + 4] + wb.y * h2s[v][k + 5] +
                  wb.z * h2s[v][k + 6] + wb.w * h2s[v][k + 7];
      }
    }
    float wrr[8];
    const float* wp = Wres + (size_t)t * 8;
#pragma unroll
    for (int c = 0; c < 8; ++c) wrr[c] = wp[c];
#pragma unroll
    for (int v = 0; v < NV; ++v) {
#pragma unroll
      for (int c = 0; c < 8; ++c) acc[v] += wrr[c] * rmag[v][c];
    }
#pragma unroll
    for (int v = 0; v < NV; ++v) {
      int n = n0 + v;
      if (n < N) out[(size_t)n * 64 + t] = acc[v];
    }
  }
}

extern "C" void kernel_launch(void* const* d_in, const int* in_sizes, int n_in,
                              void* d_out, int out_size, void* d_ws, size_t ws_size,
                              hipStream_t stream) {
  (void)n_in; (void)out_size; (void)ws_size;
  const float* x_re = (const float*)d_in[0];
  const float* x_im = (const float*)d_in[1];
  const int* edges = (const int*)d_in[2];
  const float* sten_re = (const float*)d_in[3];
  const float* sten_im = (const float*)d_in[4];
  const float* ln_re = (const float*)d_in[5];
  const float* ln_im = (const float*)d_in[6];
  const float* wxp_re = (const float*)d_in[7];
  const float* wxp_im = (const float*)d_in[8];
  const float* W_conv = (const float*)d_in[9];
  const float* phase = (const float*)d_in[10];
  const float* b_nl = (const float*)d_in[11];
  const float* W1 = (const float*)d_in[12];
  const float* b1 = (const float*)d_in[13];
  const float* W2 = (const float*)d_in[14];
  const float* b2 = (const float*)d_in[15];
  const float* W3 = (const float*)d_in[16];
  const float* b3 = (const float*)d_in[17];
  const float* Wres = (const float*)d_in[18];
  const float* bres = (const float*)d_in[19];
  float* out = (float*)d_out;

  int N = in_sizes[0] / 8;
  int E = in_sizes[2] / 2;

  float* ws = (float*)d_ws;
  float2* g2 = (float2*)ws;                       // N*144 float2 = N*288 floats
  float* y = ws + (size_t)N * 288;                // N*16 floats
  int* cnt = (int*)(y + (size_t)N * 16);          // N ints
  int* offs = cnt + N;                            // N+1 ints
  int* cur = offs + N + 1;                        // N ints
  int* elist = cur + N;                           // E ints

  hipMemsetAsync(cnt, 0, (size_t)N * sizeof(int), stream);

  g_kernel<<<(N * 144 + 255) / 256, 256, 0, stream>>>(x_re, x_im, W_conv, phase, g2, N);
  count_kernel<<<(E + 255) / 256, 256, 0, stream>>>(edges, cnt, E);
  scan_kernel<<<1, 1024, 0, stream>>>(cnt, offs, cur, N);
  fill_kernel<<<(E + 255) / 256, 256, 0, stream>>>(edges, cur, elist, E);
  edge_conv_gather<<<N, 64, 0, stream>>>(edges, offs, elist, sten_re, sten_im,
                                         g2, b_nl, y, N);
  hist_mlp_kernel<<<(N + NV - 1) / NV, 256, 0, stream>>>(
      edges, offs, elist, y, ln_re, ln_im, wxp_re, wxp_im, x_re, x_im,
      W1, b1, W2, b2, W3, b3, Wres, bres, out, N);
}

// Round 3
// 671.073 us; speedup vs baseline: 2.6776x; 1.4531x over previous
//
#include <hip/hip_runtime.h>
#include <math.h>

#define EPSF 1e-6f

__device__ __constant__ int DISK[37] = {
    2, 3, 4,
    8, 9, 10, 11, 12,
    14, 15, 16, 17, 18, 19, 20,
    21, 22, 23, 24, 25, 26, 27,
    28, 29, 30, 31, 32, 33, 34,
    36, 37, 38, 39, 40,
    44, 45, 46};

// ---------------------------------------------------------------------------
// g[n, d, rm] = sum_c Wc[d, c, rm] * x[n, c];  Wc = W_conv * exp(i*phase)
// g stored interleaved float2, layout [n][d*18+rm]
// ---------------------------------------------------------------------------
__global__ __launch_bounds__(256) void g_kernel(
    const float* __restrict__ x_re, const float* __restrict__ x_im,
    const float* __restrict__ W_conv, const float* __restrict__ phase,
    float2* __restrict__ g2, int N) {
  __shared__ float wc_re[1152];
  __shared__ float wc_im[1152];
  int t = threadIdx.x;
  for (int i = t; i < 1152; i += 256) {
    int dc = i / 18;
    float w = W_conv[i];
    float ph = phase[dc];
    wc_re[i] = w * cosf(ph);
    wc_im[i] = w * sinf(ph);
  }
  __syncthreads();
  int gid = blockIdx.x * 256 + t;
  int total = N * 144;
  if (gid >= total) return;
  int n = gid / 144;
  int q = gid - n * 144;  // d*18 + rm
  int d = q / 18;
  int rm = q - d * 18;
  const float* xr = x_re + n * 8;
  const float* xi = x_im + n * 8;
  float ar = 0.f, ai = 0.f;
#pragma unroll
  for (int c = 0; c < 8; ++c) {
    float wr = wc_re[(d * 8 + c) * 18 + rm];
    float wi = wc_im[(d * 8 + c) * 18 + rm];
    float vr = xr[c], vi = xi[c];
    ar += wr * vr - wi * vi;
    ai += wr * vi + wi * vr;
  }
  g2[gid] = make_float2(ar, ai);
}

// ---------------------------------------------------------------------------
// CSR build
// ---------------------------------------------------------------------------
__global__ __launch_bounds__(256) void count_kernel(const int* __restrict__ edges,
                                                    int* __restrict__ cnt, int E) {
  int e = blockIdx.x * 256 + threadIdx.x;
  if (e >= E) return;
  atomicAdd(&cnt[edges[2 * e + 1]], 1);
}

__global__ __launch_bounds__(1024) void scan_kernel(const int* __restrict__ cnt,
                                                    int* __restrict__ offs,
                                                    int* __restrict__ cur, int N) {
  __shared__ int sums[1024];
  int t = threadIdx.x;
  int per = (N + 1023) / 1024;
  int base = t * per;
  int s = 0;
  for (int i = 0; i < per; ++i) {
    int idx = base + i;
    if (idx < N) s += cnt[idx];
  }
  sums[t] = s;
  __syncthreads();
  for (int d = 1; d < 1024; d <<= 1) {
    int v = (t >= d) ? sums[t - d] : 0;
    __syncthreads();
    sums[t] += v;
    __syncthreads();
  }
  int run = (t == 0) ? 0 : sums[t - 1];
  for (int i = 0; i < per; ++i) {
    int idx = base + i;
    if (idx < N) {
      int c = cnt[idx];
      offs[idx] = run;
      cur[idx] = run;
      run += c;
    }
  }
  if (t == 1023) offs[N] = sums[1023];
}

// fill: CSR edge list + packed per-slot payload (src, wxp, ln) for coalesced
// downstream reads
__global__ __launch_bounds__(256) void fill_kernel(
    const int* __restrict__ edges, int* __restrict__ cur,
    const float* __restrict__ wxp_re, const float* __restrict__ wxp_im,
    const float* __restrict__ ln_re, const float* __restrict__ ln_im,
    int* __restrict__ elist, int* __restrict__ src_l,
    float4* __restrict__ wln, int E) {
  int e = blockIdx.x * 256 + threadIdx.x;
  if (e >= E) return;
  int src = edges[2 * e];
  int dst = edges[2 * e + 1];
  int pos = atomicAdd(&cur[dst], 1);
  elist[pos] = e;
  src_l[pos] = src;
  wln[pos] = make_float4(wxp_re[e], wxp_im[e], ln_re[e], ln_im[e]);
}

// ---------------------------------------------------------------------------
// Gather edge conv + nonlinearity: 4 nodes per 256-thread block, 1 wave each.
// lane = es*8 + d; butterfly-reduce over es.
// ---------------------------------------------------------------------------
__global__ __launch_bounds__(256, 4) void edge_conv_gather(
    const int* __restrict__ offs, const int* __restrict__ elist,
    const int* __restrict__ src_l,
    const float* __restrict__ sten_re, const float* __restrict__ sten_im,
    const float2* __restrict__ g2, const float* __restrict__ b_nl,
    float* __restrict__ y, int N) {
  int t = threadIdx.x;
  int n = blockIdx.x * 4 + (t >> 6);
  if (n >= N) return;
  int lane = t & 63;
  int es = lane >> 3;
  int d = lane & 7;
  int beg = offs[n], end = offs[n + 1];
  float ar = 0.f, ai = 0.f;
  for (int i = beg + es; i < end; i += 8) {
    int e = elist[i];
    int src = src_l[i];
    float sr[18], si[18];
    const float2* pre = (const float2*)(sten_re + (size_t)e * 18);
    const float2* pim = (const float2*)(sten_im + (size_t)e * 18);
#pragma unroll
    for (int p = 0; p < 9; ++p) {
      float2 a = pre[p];
      float2 b = pim[p];
      sr[2 * p] = a.x; sr[2 * p + 1] = a.y;
      si[2 * p] = b.x; si[2 * p + 1] = b.y;
    }
    const float4* gq = (const float4*)(g2 + (size_t)src * 144 + d * 18);
#pragma unroll
    for (int p = 0; p < 9; ++p) {
      float4 gv = gq[p];
      int rm = 2 * p;
      ar += sr[rm] * gv.x - si[rm] * gv.y;
      ai += sr[rm] * gv.y + si[rm] * gv.x;
      ar += sr[rm + 1] * gv.z - si[rm + 1] * gv.w;
      ai += sr[rm + 1] * gv.w + si[rm + 1] * gv.z;
    }
  }
  ar += __shfl_xor(ar, 8);
  ai += __shfl_xor(ai, 8);
  ar += __shfl_xor(ar, 16);
  ai += __shfl_xor(ai, 16);
  ar += __shfl_xor(ar, 32);
  ai += __shfl_xor(ai, 32);
  if (lane < 8) {
    float mag = sqrtf(ar * ar + ai * ai);
    float s = fmaxf(mag + b_nl[d], 0.f) / (mag + EPSF);
    y[(size_t)n * 16 + 2 * d] = ar * s;
    y[(size_t)n * 16 + 2 * d + 1] = ai * s;
  }
}

// ---------------------------------------------------------------------------
// Histogram: 8 nodes/block, 32 lanes/node, d-major padded LDS layout.
// hl[v*417 + d*52 + bin]  -> atomic banks spread by bin (not stuck on 4).
// Writes desc[n][296] (disk-gathered, (d,k) order) to global.
// ---------------------------------------------------------------------------
__global__ __launch_bounds__(256, 4) void hist_kernel(
    const int* __restrict__ offs, const int* __restrict__ src_l,
    const float4* __restrict__ wln, const float* __restrict__ y,
    float* __restrict__ desc_g, int N) {
  __shared__ float hl[8 * 417];
  int t = threadIdx.x;
  int n0 = blockIdx.x * 8;
  for (int i = t; i < 8 * 417; i += 256) hl[i] = 0.f;
  __syncthreads();

  int v = t >> 5;
  int l = t & 31;
  int n = n0 + v;
  if (n < N) {
    int beg = offs[n], end = offs[n + 1];
    float* hv = hl + v * 417;
    for (int i = beg + l; i < end; i += 32) {
      int src = src_l[i];
      float4 w4 = wln[i];
      float wr = w4.x, wi = w4.y, lr = w4.z, li = w4.w;
      const float4* yp = (const float4*)(y + (size_t)src * 16);
#pragma unroll
      for (int p = 0; p < 4; ++p) {
        float4 yv = yp[p];
#pragma unroll
        for (int h = 0; h < 2; ++h) {
          int d = 2 * p + h;
          float yr = h ? yv.z : yv.x;
          float yi = h ? yv.w : yv.y;
          float fr = yr * wr - yi * wi;
          float fi = yr * wi + yi * wr;
          float fm = sqrtf(fr * fr + fi * fi);
          float inv = 1.f / (fm + EPSF);
          float cr = (lr * fr + li * fi) * inv;
          float ci = (li * fr - lr * fi) * inv;
          float gx = cr * 3.f + 3.f;
          float gy = ci * 3.f + 3.f;
          float x0f = floorf(gx), y0f = floorf(gy);
          float wx = gx - x0f, wy = gy - y0f;
          int x0i = min(max((int)x0f, 0), 6);
          int x1i = min(x0i + 1, 6);
          int y0i = min(max((int)y0f, 0), 6);
          int y1i = min(y0i + 1, 6);
          float* hd = hv + d * 52;
          atomicAdd(hd + x0i * 7 + y0i, fm * (1.f - wx) * (1.f - wy));
          atomicAdd(hd + x1i * 7 + y0i, fm * wx * (1.f - wy));
          atomicAdd(hd + x0i * 7 + y1i, fm * (1.f - wx) * wy);
          atomicAdd(hd + x1i * 7 + y1i, fm * wx * wy);
        }
      }
    }
  }
  __syncthreads();

  // disk gather -> desc[n][d*37+k], coalesced global write
  for (int i = t; i < 8 * 296; i += 256) {
    int vv = i / 296;
    int q = i - vv * 296;
    int d = q / 37;
    int k = q - d * 37;
    int nn = n0 + vv;
    if (nn < N) desc_g[(size_t)nn * 296 + q] = hl[vv * 417 + d * 52 + DISK[k]];
  }
}

// ---------------------------------------------------------------------------
// MLP: 16 nodes per 256-thread block, all threads active each layer.
// ---------------------------------------------------------------------------
__global__ __launch_bounds__(256, 4) void mlp_kernel(
    const float* __restrict__ desc_g,
    const float* __restrict__ x_re, const float* __restrict__ x_im,
    const float* __restrict__ W1, const float* __restrict__ b1,
    const float* __restrict__ W2, const float* __restrict__ b2,
    const float* __restrict__ W3, const float* __restrict__ b3,
    const float* __restrict__ Wres, const float* __restrict__ bres,
    float* __restrict__ out, int N) {
  __shared__ float ds[16][300];
  __shared__ float h1s[16][128];
  __shared__ float h2s[16][64];
  __shared__ float rmag[16][8];
  int t = threadIdx.x;
  int n0 = blockIdx.x * 16;

  for (int i = t; i < 16 * 296; i += 256) {
    int v = i / 296;
    int k = i - v * 296;
    int n = n0 + v;
    ds[v][k] = (n < N) ? desc_g[(size_t)n * 296 + k] : 0.f;
  }
  if (t < 128) {
    int v = t >> 3, c = t & 7;
    int n = n0 + v;
    if (n < N) {
      float xr = x_re[n * 8 + c], xi = x_im[n * 8 + c];
      rmag[v][c] = sqrtf(xr * xr + xi * xi + EPSF);
    } else {
      rmag[v][c] = 0.f;
    }
  }
  __syncthreads();

  // Layer 1: 128 j x 2 vgroups of 8 nodes
  {
    int j = t & 127;
    int v0 = (t >> 7) * 8;
    float acc[8];
    float bb = b1[j];
#pragma unroll
    for (int u = 0; u < 8; ++u) acc[u] = bb;
    const float* wrow = W1 + (size_t)j * 296;
    for (int k = 0; k < 296; k += 8) {
      float4 wa = *(const float4*)(wrow + k);
      float4 wb = *(const float4*)(wrow + k + 4);
#pragma unroll
      for (int u = 0; u < 8; ++u) {
        const float4* dv = (const float4*)(&ds[v0 + u][k]);
        float4 da = dv[0], db = dv[1];
        acc[u] += wa.x * da.x + wa.y * da.y + wa.z * da.z + wa.w * da.w +
                  wb.x * db.x + wb.y * db.y + wb.z * db.z + wb.w * db.w;
      }
    }
#pragma unroll
    for (int u = 0; u < 8; ++u) h1s[v0 + u][j] = fmaxf(acc[u], 0.f);
  }
  __syncthreads();

  // Layer 2: 64 j x 4 vgroups of 4 nodes
  {
    int j = t & 63;
    int v0 = (t >> 6) * 4;
    float acc[4];
    float bb = b2[j];
#pragma unroll
    for (int u = 0; u < 4; ++u) acc[u] = bb;
    const float* wrow = W2 + (size_t)j * 128;
    for (int k = 0; k < 128; k += 8) {
      float4 wa = *(const float4*)(wrow + k);
      float4 wb = *(const float4*)(wrow + k + 4);
#pragma unroll
      for (int u = 0; u < 4; ++u) {
        const float4* dv = (const float4*)(&h1s[v0 + u][k]);
        float4 da = dv[0], db = dv[1];
        acc[u] += wa.x * da.x + wa.y * da.y + wa.z * da.z + wa.w * da.w +
                  wb.x * db.x + wb.y * db.y + wb.z * db.z + wb.w * db.w;
      }
    }
#pragma unroll
    for (int u = 0; u < 4; ++u) h2s[v0 + u][j] = fmaxf(acc[u], 0.f);
  }
  __syncthreads();

  // Layer 3 + residual: 64 j x 4 vgroups of 4 nodes
  {
    int j = t & 63;
    int v0 = (t >> 6) * 4;
    float acc[4];
    float bb = b3[j] + bres[j];
#pragma unroll
    for (int u = 0; u < 4; ++u) acc[u] = bb;
    const float* wrow = W3 + (size_t)j * 64;
    for (int k = 0; k < 64; k += 8) {
      float4 wa = *(const float4*)(wrow + k);
      float4 wb = *(const float4*)(wrow + k + 4);
#pragma unroll
      for (int u = 0; u < 4; ++u) {
        const float4* dv = (const float4*)(&h2s[v0 + u][k]);
        float4 da = dv[0], db = dv[1];
        acc[u] += wa.x * da.x + wa.y * da.y + wa.z * da.z + wa.w * da.w +
                  wb.x * db.x + wb.y * db.y + wb.z * db.z + wb.w * db.w;
      }
    }
    float wrr[8];
    const float* wp = Wres + (size_t)j * 8;
#pragma unroll
    for (int c = 0; c < 8; ++c) wrr[c] = wp[c];
#pragma unroll
    for (int u = 0; u < 4; ++u) {
#pragma unroll
      for (int c = 0; c < 8; ++c) acc[u] += wrr[c] * rmag[v0 + u][c];
    }
#pragma unroll
    for (int u = 0; u < 4; ++u) {
      int n = n0 + v0 + u;
      if (n < N) out[(size_t)n * 64 + (t & 63)] = acc[u];
    }
  }
}

extern "C" void kernel_launch(void* const* d_in, const int* in_sizes, int n_in,
                              void* d_out, int out_size, void* d_ws, size_t ws_size,
                              hipStream_t stream) {
  (void)n_in; (void)out_size; (void)ws_size;
  const float* x_re = (const float*)d_in[0];
  const float* x_im = (const float*)d_in[1];
  const int* edges = (const int*)d_in[2];
  const float* sten_re = (const float*)d_in[3];
  const float* sten_im = (const float*)d_in[4];
  const float* ln_re = (const float*)d_in[5];
  const float* ln_im = (const float*)d_in[6];
  const float* wxp_re = (const float*)d_in[7];
  const float* wxp_im = (const float*)d_in[8];
  const float* W_conv = (const float*)d_in[9];
  const float* phase = (const float*)d_in[10];
  const float* b_nl = (const float*)d_in[11];
  const float* W1 = (const float*)d_in[12];
  const float* b1 = (const float*)d_in[13];
  const float* W2 = (const float*)d_in[14];
  const float* b2 = (const float*)d_in[15];
  const float* W3 = (const float*)d_in[16];
  const float* b3 = (const float*)d_in[17];
  const float* Wres = (const float*)d_in[18];
  const float* bres = (const float*)d_in[19];
  float* out = (float*)d_out;

  int N = in_sizes[0] / 8;
  int E = in_sizes[2] / 2;

  // workspace layout (float4-aligned first)
  float* ws = (float*)d_ws;
  float4* wln = (float4*)ws;                          // E float4
  float* g2f = ws + (size_t)E * 4;                    // N*288 floats
  float2* g2 = (float2*)g2f;
  float* y = g2f + (size_t)N * 288;                   // N*16
  float* desc_g = y + (size_t)N * 16;                 // N*296
  int* cnt = (int*)(desc_g + (size_t)N * 296);        // N
  int* offs = cnt + N;                                // N+1
  int* cur = offs + N + 1;                            // N
  int* elist = cur + N;                               // E
  int* src_l = elist + E;                             // E

  hipMemsetAsync(cnt, 0, (size_t)N * sizeof(int), stream);

  g_kernel<<<(N * 144 + 255) / 256, 256, 0, stream>>>(x_re, x_im, W_conv, phase, g2, N);
  count_kernel<<<(E + 255) / 256, 256, 0, stream>>>(edges, cnt, E);
  scan_kernel<<<1, 1024, 0, stream>>>(cnt, offs, cur, N);
  fill_kernel<<<(E + 255) / 256, 256, 0, stream>>>(edges, cur, wxp_re, wxp_im,
                                                   ln_re, ln_im, elist, src_l, wln, E);
  edge_conv_gather<<<(N + 3) / 4, 256, 0, stream>>>(offs, elist, src_l, sten_re,
                                                    sten_im, g2, b_nl, y, N);
  hist_kernel<<<(N + 7) / 8, 256, 0, stream>>>(offs, src_l, wln, y, desc_g, N);
  mlp_kernel<<<(N + 15) / 16, 256, 0, stream>>>(desc_g, x_re, x_im, W1, b1, W2, b2,
                                                W3, b3, Wres, bres, out, N);
}

// Round 4
// 659.170 us; speedup vs baseline: 2.7260x; 1.0181x over previous
//
#include <hip/hip_runtime.h>
#include <math.h>

#define EPSF 1e-6f

__device__ __constant__ int DISK[37] = {
    2, 3, 4,
    8, 9, 10, 11, 12,
    14, 15, 16, 17, 18, 19, 20,
    21, 22, 23, 24, 25, 26, 27,
    28, 29, 30, 31, 32, 33, 34,
    36, 37, 38, 39, 40,
    44, 45, 46};

// ---------------------------------------------------------------------------
// g[n, d, rm] = sum_c Wc[d, c, rm] * x[n, c];  Wc = W_conv * exp(i*phase)
// g stored interleaved float2, layout [n][d*18+rm]
// ---------------------------------------------------------------------------
__global__ __launch_bounds__(256) void g_kernel(
    const float* __restrict__ x_re, const float* __restrict__ x_im,
    const float* __restrict__ W_conv, const float* __restrict__ phase,
    float2* __restrict__ g2, int N) {
  __shared__ float wc_re[1152];
  __shared__ float wc_im[1152];
  int t = threadIdx.x;
  for (int i = t; i < 1152; i += 256) {
    int dc = i / 18;
    float w = W_conv[i];
    float ph = phase[dc];
    wc_re[i] = w * cosf(ph);
    wc_im[i] = w * sinf(ph);
  }
  __syncthreads();
  int gid = blockIdx.x * 256 + t;
  int total = N * 144;
  if (gid >= total) return;
  int n = gid / 144;
  int q = gid - n * 144;  // d*18 + rm
  int d = q / 18;
  int rm = q - d * 18;
  const float* xr = x_re + n * 8;
  const float* xi = x_im + n * 8;
  float ar = 0.f, ai = 0.f;
#pragma unroll
  for (int c = 0; c < 8; ++c) {
    float wr = wc_re[(d * 8 + c) * 18 + rm];
    float wi = wc_im[(d * 8 + c) * 18 + rm];
    float vr = xr[c], vi = xi[c];
    ar += wr * vr - wi * vi;
    ai += wr * vi + wi * vr;
  }
  g2[gid] = make_float2(ar, ai);
}

// ---------------------------------------------------------------------------
// CSR build: count both dst (cnt) and src (scnt) degrees in one pass
// ---------------------------------------------------------------------------
__global__ __launch_bounds__(256) void count_kernel(const int* __restrict__ edges,
                                                    int* __restrict__ cnt,
                                                    int* __restrict__ scnt, int E) {
  int e = blockIdx.x * 256 + threadIdx.x;
  if (e >= E) return;
  atomicAdd(&cnt[edges[2 * e + 1]], 1);
  atomicAdd(&scnt[edges[2 * e]], 1);
}

// Single-block dual exclusive scan: cnt->offs,cur and scnt->soffs,scur
__global__ __launch_bounds__(1024) void scan_dual_kernel(
    const int* __restrict__ cnt, int* __restrict__ offs, int* __restrict__ cur,
    const int* __restrict__ scnt, int* __restrict__ soffs, int* __restrict__ scur,
    int N) {
  __shared__ int sums[1024];
  int t = threadIdx.x;
  int per = (N + 1023) / 1024;
  for (int pass = 0; pass < 2; ++pass) {
    const int* c = pass ? scnt : cnt;
    int* o = pass ? soffs : offs;
    int* u = pass ? scur : cur;
    int base = t * per;
    int s = 0;
    for (int i = 0; i < per; ++i) {
      int idx = base + i;
      if (idx < N) s += c[idx];
    }
    sums[t] = s;
    __syncthreads();
    for (int d = 1; d < 1024; d <<= 1) {
      int v = (t >= d) ? sums[t - d] : 0;
      __syncthreads();
      sums[t] += v;
      __syncthreads();
    }
    int run = (t == 0) ? 0 : sums[t - 1];
    for (int i = 0; i < per; ++i) {
      int idx = base + i;
      if (idx < N) {
        int cc = c[idx];
        o[idx] = run;
        u[idx] = run;
        run += cc;
      }
    }
    if (t == 1023) o[N] = sums[1023];
    __syncthreads();
  }
}

// fill both CSRs; sdpos links src-slot -> dst-slot so conv can write ye
// directly into the dst-CSR slot.
__global__ __launch_bounds__(256) void fill_kernel(
    const int* __restrict__ edges, int* __restrict__ cur, int* __restrict__ scur,
    const float* __restrict__ wxp_re, const float* __restrict__ wxp_im,
    const float* __restrict__ ln_re, const float* __restrict__ ln_im,
    int* __restrict__ src_l, float4* __restrict__ wln,
    int* __restrict__ selist, int* __restrict__ sdpos, int E) {
  int e = blockIdx.x * 256 + threadIdx.x;
  if (e >= E) return;
  int src = edges[2 * e];
  int dst = edges[2 * e + 1];
  int pos = atomicAdd(&cur[dst], 1);
  src_l[pos] = src;
  wln[pos] = make_float4(wxp_re[e], wxp_im[e], ln_re[e], ln_im[e]);
  int pos2 = atomicAdd(&scur[src], 1);
  selist[pos2] = e;
  sdpos[pos2] = pos;
}

// ---------------------------------------------------------------------------
// Edge conv in src-grouped order: wave per src node, g-row held in VGPRs,
// reused for all outgoing edges. Writes ye (8 complex) to dst-CSR slot.
// lane = es*8 + d.
// ---------------------------------------------------------------------------
__global__ __launch_bounds__(256, 4) void conv_src_kernel(
    const int* __restrict__ soffs, const int* __restrict__ selist,
    const int* __restrict__ sdpos,
    const float* __restrict__ sten_re, const float* __restrict__ sten_im,
    const float2* __restrict__ g2, float2* __restrict__ yebuf, int N) {
  int t = threadIdx.x;
  int m = blockIdx.x * 4 + (t >> 6);
  if (m >= N) return;
  int lane = t & 63;
  int es = lane >> 3;
  int d = lane & 7;
  float gr[18], gi[18];
  const float4* gq = (const float4*)(g2 + (size_t)m * 144 + d * 18);
#pragma unroll
  for (int p = 0; p < 9; ++p) {
    float4 v = gq[p];
    gr[2 * p] = v.x; gi[2 * p] = v.y;
    gr[2 * p + 1] = v.z; gi[2 * p + 1] = v.w;
  }
  int beg = soffs[m], end = soffs[m + 1];
  for (int i = beg + es; i < end; i += 8) {
    int e = selist[i];
    int ds = sdpos[i];
    const float2* pre = (const float2*)(sten_re + (size_t)e * 18);
    const float2* pim = (const float2*)(sten_im + (size_t)e * 18);
    float ar = 0.f, ai = 0.f;
#pragma unroll
    for (int p = 0; p < 9; ++p) {
      float2 a = pre[p];
      float2 b = pim[p];
      int rm = 2 * p;
      ar += a.x * gr[rm] - b.x * gi[rm];
      ai += a.x * gi[rm] + b.x * gr[rm];
      ar += a.y * gr[rm + 1] - b.y * gi[rm + 1];
      ai += a.y * gi[rm + 1] + b.y * gr[rm + 1];
    }
    yebuf[(size_t)ds * 8 + d] = make_float2(ar, ai);
  }
}

// ---------------------------------------------------------------------------
// Reduce ye over each node's contiguous dst-slot range + nonlinearity -> y
// ---------------------------------------------------------------------------
__global__ __launch_bounds__(256, 4) void ye_reduce_kernel(
    const int* __restrict__ offs, const float2* __restrict__ yebuf,
    const float* __restrict__ b_nl, float* __restrict__ y, int N) {
  int t = threadIdx.x;
  int n = blockIdx.x * 4 + (t >> 6);
  if (n >= N) return;
  int lane = t & 63;
  int es = lane >> 3;
  int d = lane & 7;
  int beg = offs[n], end = offs[n + 1];
  float ar = 0.f, ai = 0.f;
  for (int i = beg + es; i < end; i += 8) {
    float2 v = yebuf[(size_t)i * 8 + d];
    ar += v.x;
    ai += v.y;
  }
  ar += __shfl_xor(ar, 8);
  ai += __shfl_xor(ai, 8);
  ar += __shfl_xor(ar, 16);
  ai += __shfl_xor(ai, 16);
  ar += __shfl_xor(ar, 32);
  ai += __shfl_xor(ai, 32);
  if (lane < 8) {
    float mag = sqrtf(ar * ar + ai * ai);
    float s = fmaxf(mag + b_nl[d], 0.f) / (mag + EPSF);
    y[(size_t)n * 16 + 2 * d] = ar * s;
    y[(size_t)n * 16 + 2 * d + 1] = ai * s;
  }
}

// ---------------------------------------------------------------------------
// Histogram: 8 nodes/block, 32 lanes/node, d-major padded LDS layout.
// Writes desc[n][296] (disk-gathered, (d,k) order) to global.
// ---------------------------------------------------------------------------
__global__ __launch_bounds__(256, 4) void hist_kernel(
    const int* __restrict__ offs, const int* __restrict__ src_l,
    const float4* __restrict__ wln, const float* __restrict__ y,
    float* __restrict__ desc_g, int N) {
  __shared__ float hl[8 * 417];
  int t = threadIdx.x;
  int n0 = blockIdx.x * 8;
  for (int i = t; i < 8 * 417; i += 256) hl[i] = 0.f;
  __syncthreads();

  int v = t >> 5;
  int l = t & 31;
  int n = n0 + v;
  if (n < N) {
    int beg = offs[n], end = offs[n + 1];
    float* hv = hl + v * 417;
    for (int i = beg + l; i < end; i += 32) {
      int src = src_l[i];
      float4 w4 = wln[i];
      float wr = w4.x, wi = w4.y, lr = w4.z, li = w4.w;
      const float4* yp = (const float4*)(y + (size_t)src * 16);
#pragma unroll
      for (int p = 0; p < 4; ++p) {
        float4 yv = yp[p];
#pragma unroll
        for (int h = 0; h < 2; ++h) {
          int d = 2 * p + h;
          float yr = h ? yv.z : yv.x;
          float yi = h ? yv.w : yv.y;
          float fr = yr * wr - yi * wi;
          float fi = yr * wi + yi * wr;
          float fm = sqrtf(fr * fr + fi * fi);
          float inv = 1.f / (fm + EPSF);
          float cr = (lr * fr + li * fi) * inv;
          float ci = (li * fr - lr * fi) * inv;
          float gx = cr * 3.f + 3.f;
          float gy = ci * 3.f + 3.f;
          float x0f = floorf(gx), y0f = floorf(gy);
          float wx = gx - x0f, wy = gy - y0f;
          int x0i = min(max((int)x0f, 0), 6);
          int x1i = min(x0i + 1, 6);
          int y0i = min(max((int)y0f, 0), 6);
          int y1i = min(y0i + 1, 6);
          float* hd = hv + d * 52;
          atomicAdd(hd + x0i * 7 + y0i, fm * (1.f - wx) * (1.f - wy));
          atomicAdd(hd + x1i * 7 + y0i, fm * wx * (1.f - wy));
          atomicAdd(hd + x0i * 7 + y1i, fm * (1.f - wx) * wy);
          atomicAdd(hd + x1i * 7 + y1i, fm * wx * wy);
        }
      }
    }
  }
  __syncthreads();

  for (int i = t; i < 8 * 296; i += 256) {
    int vv = i / 296;
    int q = i - vv * 296;
    int d = q / 37;
    int k = q - d * 37;
    int nn = n0 + vv;
    if (nn < N) desc_g[(size_t)nn * 296 + q] = hl[vv * 417 + d * 52 + DISK[k]];
  }
}

// ---------------------------------------------------------------------------
// MLP: 16 nodes per 256-thread block, all threads active each layer.
// ---------------------------------------------------------------------------
__global__ __launch_bounds__(256, 4) void mlp_kernel(
    const float* __restrict__ desc_g,
    const float* __restrict__ x_re, const float* __restrict__ x_im,
    const float* __restrict__ W1, const float* __restrict__ b1,
    const float* __restrict__ W2, const float* __restrict__ b2,
    const float* __restrict__ W3, const float* __restrict__ b3,
    const float* __restrict__ Wres, const float* __restrict__ bres,
    float* __restrict__ out, int N) {
  __shared__ float ds[16][300];
  __shared__ float h1s[16][128];
  __shared__ float h2s[16][64];
  __shared__ float rmag[16][8];
  int t = threadIdx.x;
  int n0 = blockIdx.x * 16;

  for (int i = t; i < 16 * 296; i += 256) {
    int v = i / 296;
    int k = i - v * 296;
    int n = n0 + v;
    ds[v][k] = (n < N) ? desc_g[(size_t)n * 296 + k] : 0.f;
  }
  if (t < 128) {
    int v = t >> 3, c = t & 7;
    int n = n0 + v;
    if (n < N) {
      float xr = x_re[n * 8 + c], xi = x_im[n * 8 + c];
      rmag[v][c] = sqrtf(xr * xr + xi * xi + EPSF);
    } else {
      rmag[v][c] = 0.f;
    }
  }
  __syncthreads();

  {
    int j = t & 127;
    int v0 = (t >> 7) * 8;
    float acc[8];
    float bb = b1[j];
#pragma unroll
    for (int u = 0; u < 8; ++u) acc[u] = bb;
    const float* wrow = W1 + (size_t)j * 296;
    for (int k = 0; k < 296; k += 8) {
      float4 wa = *(const float4*)(wrow + k);
      float4 wb = *(const float4*)(wrow + k + 4);
#pragma unroll
      for (int u = 0; u < 8; ++u) {
        const float4* dv = (const float4*)(&ds[v0 + u][k]);
        float4 da = dv[0], db = dv[1];
        acc[u] += wa.x * da.x + wa.y * da.y + wa.z * da.z + wa.w * da.w +
                  wb.x * db.x + wb.y * db.y + wb.z * db.z + wb.w * db.w;
      }
    }
#pragma unroll
    for (int u = 0; u < 8; ++u) h1s[v0 + u][j] = fmaxf(acc[u], 0.f);
  }
  __syncthreads();

  {
    int j = t & 63;
    int v0 = (t >> 6) * 4;
    float acc[4];
    float bb = b2[j];
#pragma unroll
    for (int u = 0; u < 4; ++u) acc[u] = bb;
    const float* wrow = W2 + (size_t)j * 128;
    for (int k = 0; k < 128; k += 8) {
      float4 wa = *(const float4*)(wrow + k);
      float4 wb = *(const float4*)(wrow + k + 4);
#pragma unroll
      for (int u = 0; u < 4; ++u) {
        const float4* dv = (const float4*)(&h1s[v0 + u][k]);
        float4 da = dv[0], db = dv[1];
        acc[u] += wa.x * da.x + wa.y * da.y + wa.z * da.z + wa.w * da.w +
                  wb.x * db.x + wb.y * db.y + wb.z * db.z + wb.w * db.w;
      }
    }
#pragma unroll
    for (int u = 0; u < 4; ++u) h2s[v0 + u][j] = fmaxf(acc[u], 0.f);
  }
  __syncthreads();

  {
    int j = t & 63;
    int v0 = (t >> 6) * 4;
    float acc[4];
    float bb = b3[j] + bres[j];
#pragma unroll
    for (int u = 0; u < 4; ++u) acc[u] = bb;
    const float* wrow = W3 + (size_t)j * 64;
    for (int k = 0; k < 64; k += 8) {
      float4 wa = *(const float4*)(wrow + k);
      float4 wb = *(const float4*)(wrow + k + 4);
#pragma unroll
      for (int u = 0; u < 4; ++u) {
        const float4* dv = (const float4*)(&h2s[v0 + u][k]);
        float4 da = dv[0], db = dv[1];
        acc[u] += wa.x * da.x + wa.y * da.y + wa.z * da.z + wa.w * da.w +
                  wb.x * db.x + wb.y * db.y + wb.z * db.z + wb.w * db.w;
      }
    }
    float wrr[8];
    const float* wp = Wres + (size_t)j * 8;
#pragma unroll
    for (int c = 0; c < 8; ++c) wrr[c] = wp[c];
#pragma unroll
    for (int u = 0; u < 4; ++u) {
#pragma unroll
      for (int c = 0; c < 8; ++c) acc[u] += wrr[c] * rmag[v0 + u][c];
    }
#pragma unroll
    for (int u = 0; u < 4; ++u) {
      int n = n0 + v0 + u;
      if (n < N) out[(size_t)n * 64 + (t & 63)] = acc[u];
    }
  }
}

extern "C" void kernel_launch(void* const* d_in, const int* in_sizes, int n_in,
                              void* d_out, int out_size, void* d_ws, size_t ws_size,
                              hipStream_t stream) {
  (void)n_in; (void)out_size; (void)ws_size;
  const float* x_re = (const float*)d_in[0];
  const float* x_im = (const float*)d_in[1];
  const int* edges = (const int*)d_in[2];
  const float* sten_re = (const float*)d_in[3];
  const float* sten_im = (const float*)d_in[4];
  const float* ln_re = (const float*)d_in[5];
  const float* ln_im = (const float*)d_in[6];
  const float* wxp_re = (const float*)d_in[7];
  const float* wxp_im = (const float*)d_in[8];
  const float* W_conv = (const float*)d_in[9];
  const float* phase = (const float*)d_in[10];
  const float* b_nl = (const float*)d_in[11];
  const float* W1 = (const float*)d_in[12];
  const float* b1 = (const float*)d_in[13];
  const float* W2 = (const float*)d_in[14];
  const float* b2 = (const float*)d_in[15];
  const float* W3 = (const float*)d_in[16];
  const float* b3 = (const float*)d_in[17];
  const float* Wres = (const float*)d_in[18];
  const float* bres = (const float*)d_in[19];
  float* out = (float*)d_out;

  int N = in_sizes[0] / 8;
  int E = in_sizes[2] / 2;

  // workspace layout (16B-aligned blocks first)
  float* ws = (float*)d_ws;
  float4* wln = (float4*)ws;                          // E float4
  float* g2f = ws + (size_t)E * 4;                    // N*288 floats
  float2* g2 = (float2*)g2f;
  float* y = g2f + (size_t)N * 288;                   // N*16
  float* yebuf_f = y + (size_t)N * 16;                // E*16 floats; desc_g aliases
  float2* yebuf = (float2*)yebuf_f;
  float* desc_g = yebuf_f;                            // N*296 <= E*16; ye dead by then
  int* cnt = (int*)(yebuf_f + (size_t)E * 16);        // N
  int* offs = cnt + N;                                // N+1
  int* cur = offs + N + 1;                            // N
  int* scnt = cur + N;                                // N
  int* soffs = scnt + N;                              // N+1
  int* scur = soffs + N + 1;                          // N
  int* selist = scur + N;                             // E
  int* sdpos = selist + E;                            // E
  int* src_l = sdpos + E;                             // E

  hipMemsetAsync(cnt, 0, (size_t)N * sizeof(int), stream);
  hipMemsetAsync(scnt, 0, (size_t)N * sizeof(int), stream);

  g_kernel<<<(N * 144 + 255) / 256, 256, 0, stream>>>(x_re, x_im, W_conv, phase, g2, N);
  count_kernel<<<(E + 255) / 256, 256, 0, stream>>>(edges, cnt, scnt, E);
  scan_dual_kernel<<<1, 1024, 0, stream>>>(cnt, offs, cur, scnt, soffs, scur, N);
  fill_kernel<<<(E + 255) / 256, 256, 0, stream>>>(edges, cur, scur, wxp_re, wxp_im,
                                                   ln_re, ln_im, src_l, wln,
                                                   selist, sdpos, E);
  conv_src_kernel<<<(N + 3) / 4, 256, 0, stream>>>(soffs, selist, sdpos, sten_re,
                                                   sten_im, g2, yebuf, N);
  ye_reduce_kernel<<<(N + 3) / 4, 256, 0, stream>>>(offs, yebuf, b_nl, y, N);
  hist_kernel<<<(N + 7) / 8, 256, 0, stream>>>(offs, src_l, wln, y, desc_g, N);
  mlp_kernel<<<(N + 15) / 16, 256, 0, stream>>>(desc_g, x_re, x_im, W1, b1, W2, b2,
                                                W3, b3, Wres, bres, out, N);
}